// Round 2
// baseline (307.623 us; speedup 1.0000x reference)
//
#include <hip/hip_runtime.h>

// SegmentalEmotion: per-sample sliding-window segment means.
// H: [B, T, D] f32, lengths_sec: [B] f32.
// Outputs (concat flat): S_pad [B, maxS, D] f32, mask [B, maxS] (0/1) f32.
//
// Planning (win/hop per sample) replicated on-device in float64 to match the
// numpy host planning exactly (rint == np.round half-to-even).

#define BDIM 192  // D/4 = 192 float4 lanes per row (D == 768)

__global__ __launch_bounds__(BDIM)
void seg_mean_kernel(const float4* __restrict__ H4,
                     const float*  __restrict__ lens,
                     float4* __restrict__ S4,
                     float*  __restrict__ M,
                     int T, int maxS) {
    const int D4  = BDIM;                 // 192 float4 per row
    const int b   = blockIdx.x / maxS;
    const int s   = blockIdx.x % maxS;
    const int tid = threadIdx.x;

    // ---- per-sample window plan (float64, matches numpy) ----
    double dur = (double)lens[b];
    if (dur < 0.001) dur = 0.001;
    double fps = (double)T / dur;
    long long win = (long long)rint(fps * 1.0);   // WIN_SEC = 1.0
    if (win < 1) win = 1;
    long long hop = (long long)rint(fps * 0.5);   // HOP_SEC = 0.5
    if (hop < 1) hop = 1;
    long long n = ((long long)T >= win) ? (((long long)T - win) / hop + 1) : 0;
    const bool fallback = (n == 0);
    const long long n_eff = fallback ? 1 : n;

    if (tid == 0) {
        M[(size_t)b * maxS + s] = (s < n_eff) ? 1.0f : 0.0f;
    }

    float4* out = S4 + ((size_t)b * maxS + s) * D4;

    if (s >= n_eff) {
        // masked/padded slot: reference zeroes it; d_out is poisoned each call
        out[tid] = make_float4(0.f, 0.f, 0.f, 0.f);
        return;
    }

    long long start = fallback ? 0 : (long long)s * hop;
    long long end   = fallback ? (long long)T : start + win;
    if (start > T) start = T;      // defensive clamps (match reference)
    if (end   > T) end   = T;
    long long cnt = end - start;
    if (cnt < 1) cnt = 1;

    const float4* base = H4 + (size_t)b * T * D4 + tid;
    float ax = 0.f, ay = 0.f, az = 0.f, aw = 0.f;
    for (long long t = start; t < end; ++t) {
        float4 v = base[t * D4];
        ax += v.x; ay += v.y; az += v.z; aw += v.w;
    }
    const float c = (float)cnt;
    out[tid] = make_float4(ax / c, ay / c, az / c, aw / c);
}

extern "C" void kernel_launch(void* const* d_in, const int* in_sizes, int n_in,
                              void* d_out, int out_size, void* d_ws, size_t ws_size,
                              hipStream_t stream) {
    const float* H    = (const float*)d_in[0];
    const float* lens = (const float*)d_in[1];

    const int B = in_sizes[1];                 // 32
    const int D = 768;
    const int T = in_sizes[0] / (B * D);       // 1500
    const int maxS = out_size / (B * (D + 1)); // out = B*maxS*D + B*maxS

    float* S = (float*)d_out;
    float* M = S + (size_t)B * maxS * D;

    dim3 grid(B * maxS);
    seg_mean_kernel<<<grid, BDIM, 0, stream>>>(
        (const float4*)H, lens, (float4*)S, M, T, maxS);
}

// Round 3
// 233.506 us; speedup vs baseline: 1.3174x; 1.3174x over previous
//
#include <hip/hip_runtime.h>

// SegmentalEmotion: per-sample sliding-window segment means.
// H: [B, T, D] f32, lengths_sec: [B] f32.
// Outputs (concat flat): S_pad [B, maxS, D] f32, mask [B, maxS] (0/1) f32.
//
// R2 -> R3: baseline was latency-bound (VGPR=12, no unroll, 1 outstanding
// load/wave, 161 us ~= 300 serial loads x ~1300cyc). Manual 8x unroll gives
// 8 outstanding loads per lane; grid is fully resident so wall time is the
// slowest (win=300) block. Target ~= HBM floor 134MB / 6.3TB/s ~= 21 us.

#define BDIM 192  // D/4 = 192 float4 lanes per row (D == 768)

__global__ __launch_bounds__(BDIM)
void seg_mean_kernel(const float4* __restrict__ H4,
                     const float*  __restrict__ lens,
                     float4* __restrict__ S4,
                     float*  __restrict__ M,
                     int T, int maxS) {
    const int D4  = BDIM;                 // 192 float4 per row
    const int b   = blockIdx.x / maxS;
    const int s   = blockIdx.x % maxS;
    const int tid = threadIdx.x;

    // ---- per-sample window plan (float64, matches numpy) ----
    double dur = (double)lens[b];
    if (dur < 0.001) dur = 0.001;
    double fps = (double)T / dur;
    long long win = (long long)rint(fps * 1.0);   // WIN_SEC = 1.0
    if (win < 1) win = 1;
    long long hop = (long long)rint(fps * 0.5);   // HOP_SEC = 0.5
    if (hop < 1) hop = 1;
    long long n = ((long long)T >= win) ? (((long long)T - win) / hop + 1) : 0;
    const bool fallback = (n == 0);
    const long long n_eff = fallback ? 1 : n;

    if (tid == 0) {
        M[(size_t)b * maxS + s] = (s < n_eff) ? 1.0f : 0.0f;
    }

    float4* out = S4 + ((size_t)b * maxS + s) * D4;

    if (s >= n_eff) {
        // masked/padded slot: reference zeroes it; d_out is poisoned each call
        out[tid] = make_float4(0.f, 0.f, 0.f, 0.f);
        return;
    }

    long long start = fallback ? 0 : (long long)s * hop;
    long long end   = fallback ? (long long)T : start + win;
    if (start > T) start = T;      // defensive clamps (match reference)
    if (end   > T) end   = T;
    long long cnt = end - start;
    if (cnt < 1) cnt = 1;

    const float4* base = H4 + (size_t)b * T * D4 + tid;

    float ax = 0.f, ay = 0.f, az = 0.f, aw = 0.f;
    float bx = 0.f, by = 0.f, bz = 0.f, bw = 0.f;

    long long t = start;
    // 8 independent loads in flight per lane
    for (; t + 8 <= end; t += 8) {
        float4 v0 = base[(t + 0) * D4];
        float4 v1 = base[(t + 1) * D4];
        float4 v2 = base[(t + 2) * D4];
        float4 v3 = base[(t + 3) * D4];
        float4 v4 = base[(t + 4) * D4];
        float4 v5 = base[(t + 5) * D4];
        float4 v6 = base[(t + 6) * D4];
        float4 v7 = base[(t + 7) * D4];
        ax += v0.x + v1.x + v2.x + v3.x;
        ay += v0.y + v1.y + v2.y + v3.y;
        az += v0.z + v1.z + v2.z + v3.z;
        aw += v0.w + v1.w + v2.w + v3.w;
        bx += v4.x + v5.x + v6.x + v7.x;
        by += v4.y + v5.y + v6.y + v7.y;
        bz += v4.z + v5.z + v6.z + v7.z;
        bw += v4.w + v5.w + v6.w + v7.w;
    }
    for (; t < end; ++t) {
        float4 v = base[t * D4];
        ax += v.x; ay += v.y; az += v.z; aw += v.w;
    }

    const float c = (float)cnt;
    out[tid] = make_float4((ax + bx) / c, (ay + by) / c,
                           (az + bz) / c, (aw + bw) / c);
}

extern "C" void kernel_launch(void* const* d_in, const int* in_sizes, int n_in,
                              void* d_out, int out_size, void* d_ws, size_t ws_size,
                              hipStream_t stream) {
    const float* H    = (const float*)d_in[0];
    const float* lens = (const float*)d_in[1];

    const int B = in_sizes[1];                 // 32
    const int D = 768;
    const int T = in_sizes[0] / (B * D);       // 1500
    const int maxS = out_size / (B * (D + 1)); // out = B*maxS*D + B*maxS

    float* S = (float*)d_out;
    float* M = S + (size_t)B * maxS * D;

    dim3 grid(B * maxS);
    seg_mean_kernel<<<grid, BDIM, 0, stream>>>(
        (const float4*)H, lens, (float4*)S, M, T, maxS);
}

// Round 9
// 220.671 us; speedup vs baseline: 1.3940x; 1.0582x over previous
//
#include <hip/hip_runtime.h>

// SegmentalEmotion: per-sample sliding-window segment means.
// H: [B, T, D] f32, lengths_sec: [B] f32.
// Outputs (concat flat): S_pad [B, maxS, D] f32, mask [B, maxS] (0/1) f32.
//
// R3 -> R4: R3 was critical-path/imbalance-bound (win spans 50..300 rows;
// wall = win=300 blocks' 37 serialized unroll-iters while short blocks drain
// the machine -> avg occupancy 18%, BW 1.6 TB/s). Now 4 row-groups per block
// (768 thr = 12 waves) split the window rows, LDS-reduce partials: critical
// path ~4x shorter, finer scheduling granularity, same exact traffic.

#define D4   192   // D/4 float4 lanes per row (D == 768)
#define RG   4     // row groups per block
#define BDIM (D4 * RG)

__global__ __launch_bounds__(BDIM)
void seg_mean_kernel(const float4* __restrict__ H4,
                     const float*  __restrict__ lens,
                     float4* __restrict__ S4,
                     float*  __restrict__ M,
                     int T, int maxS) {
    const int b    = blockIdx.x / maxS;
    const int s    = blockIdx.x % maxS;
    const int tid  = threadIdx.x;
    const int lane = tid % D4;   // float4 column
    const int g    = tid / D4;   // row group 0..RG-1 (contiguous 3 waves each)

    // ---- per-sample window plan (float64, matches numpy) ----
    double dur = (double)lens[b];
    if (dur < 0.001) dur = 0.001;
    double fps = (double)T / dur;
    long long win = (long long)rint(fps * 1.0);   // WIN_SEC = 1.0
    if (win < 1) win = 1;
    long long hop = (long long)rint(fps * 0.5);   // HOP_SEC = 0.5
    if (hop < 1) hop = 1;
    long long n = ((long long)T >= win) ? (((long long)T - win) / hop + 1) : 0;
    const bool fallback = (n == 0);
    const long long n_eff = fallback ? 1 : n;

    if (tid == 0) {
        M[(size_t)b * maxS + s] = (s < n_eff) ? 1.0f : 0.0f;
    }

    float4* out = S4 + ((size_t)b * maxS + s) * D4;

    if (s >= n_eff) {
        // masked/padded slot: reference zeroes it; d_out is poisoned each call
        if (g == 0) out[lane] = make_float4(0.f, 0.f, 0.f, 0.f);
        return;  // whole block exits before any __syncthreads
    }

    long long start = fallback ? 0 : (long long)s * hop;
    long long end   = fallback ? (long long)T : start + win;
    if (start > T) start = T;
    if (end   > T) end   = T;
    long long cnt = end - start;
    if (cnt < 1) cnt = 1;

    const float4* base = H4 + (size_t)b * T * D4 + lane;

    float ax = 0.f, ay = 0.f, az = 0.f, aw = 0.f;
    float bx = 0.f, by = 0.f, bz = 0.f, bw = 0.f;

    // group g covers rows start+g, start+g+RG, ... ; 8 loads in flight
    long long t = start + g;
    for (; t + 7 * RG < end; t += 8 * RG) {
        float4 v0 = base[(t + 0 * RG) * D4];
        float4 v1 = base[(t + 1 * RG) * D4];
        float4 v2 = base[(t + 2 * RG) * D4];
        float4 v3 = base[(t + 3 * RG) * D4];
        float4 v4 = base[(t + 4 * RG) * D4];
        float4 v5 = base[(t + 5 * RG) * D4];
        float4 v6 = base[(t + 6 * RG) * D4];
        float4 v7 = base[(t + 7 * RG) * D4];
        ax += v0.x + v1.x + v2.x + v3.x;
        ay += v0.y + v1.y + v2.y + v3.y;
        az += v0.z + v1.z + v2.z + v3.z;
        aw += v0.w + v1.w + v2.w + v3.w;
        bx += v4.x + v5.x + v6.x + v7.x;
        by += v4.y + v5.y + v6.y + v7.y;
        bz += v4.z + v5.z + v6.z + v7.z;
        bw += v4.w + v5.w + v6.w + v7.w;
    }
    for (; t < end; t += RG) {
        float4 v = base[t * D4];
        ax += v.x; ay += v.y; az += v.z; aw += v.w;
    }

    __shared__ float4 part[RG][D4];
    part[g][lane] = make_float4(ax + bx, ay + by, az + bz, aw + bw);
    __syncthreads();

    if (g == 0) {
        float4 p0 = part[0][lane];
        float4 p1 = part[1][lane];
        float4 p2 = part[2][lane];
        float4 p3 = part[3][lane];
        const float c = (float)cnt;
        out[lane] = make_float4((p0.x + p1.x + p2.x + p3.x) / c,
                                (p0.y + p1.y + p2.y + p3.y) / c,
                                (p0.z + p1.z + p2.z + p3.z) / c,
                                (p0.w + p1.w + p2.w + p3.w) / c);
    }
}

extern "C" void kernel_launch(void* const* d_in, const int* in_sizes, int n_in,
                              void* d_out, int out_size, void* d_ws, size_t ws_size,
                              hipStream_t stream) {
    const float* H    = (const float*)d_in[0];
    const float* lens = (const float*)d_in[1];

    const int B = in_sizes[1];                 // 32
    const int D = 768;
    const int T = in_sizes[0] / (B * D);       // 1500
    const int maxS = out_size / (B * (D + 1)); // out = B*maxS*D + B*maxS

    float* S = (float*)d_out;
    float* M = S + (size_t)B * maxS * D;

    dim3 grid(B * maxS);
    seg_mean_kernel<<<grid, BDIM, 0, stream>>>(
        (const float4*)H, lens, (float4*)S, M, T, maxS);
}

// Round 13
// 219.238 us; speedup vs baseline: 1.4031x; 1.0065x over previous
//
#include <hip/hip_runtime.h>

// SegmentalEmotion: per-sample sliding-window segment means.
// H: [B, T, D] f32, lengths_sec: [B] f32.
// Outputs (concat flat): S_pad [B, maxS, D] f32, mask [B, maxS] (0/1) f32.
//
// R4 -> R5: R4 (~77us est.) sits at ~3.8 TB/s of L2-miss traffic (290MB
// logical: win/hop=2 overlap misses per-XCD L2 because adjacent-s blocks
// scatter across XCDs). Theory: L3-path-BW-bound (~4 TB/s). Fix: bijective
// XCD swizzle (hw xcd = blockIdx.x % 8) so each XCD owns 4 consecutive
// samples; (b,s) and (b,s+1) share an XCD -> overlap hits 4MB L2.
// Row-group structure from R4 kept unchanged.

#define D4   192   // D/4 float4 lanes per row (D == 768)
#define RG   4     // row groups per block
#define BDIM (D4 * RG)

__global__ __launch_bounds__(BDIM)
void seg_mean_kernel(const float4* __restrict__ H4,
                     const float*  __restrict__ lens,
                     float4* __restrict__ S4,
                     float*  __restrict__ M,
                     int T, int maxS) {
    // ---- XCD-aware bijective swizzle (T1): hw assigns xcd = blockIdx.x % 8.
    // d = (blockIdx.x % 8) * (nwg/8) + blockIdx.x / 8 gives each XCD a
    // contiguous chunk of segment-space (4 consecutive b's when B=32).
    const int nwg = gridDim.x;
    int d;
    if ((nwg & 7) == 0) {
        const int q = nwg >> 3;
        d = (blockIdx.x & 7) * q + (blockIdx.x >> 3);
    } else {
        d = blockIdx.x;
    }
    const int b    = d / maxS;
    const int s    = d % maxS;
    const int tid  = threadIdx.x;
    const int lane = tid % D4;   // float4 column
    const int g    = tid / D4;   // row group 0..RG-1 (contiguous 3 waves each)

    // ---- per-sample window plan (float64, matches numpy) ----
    double dur = (double)lens[b];
    if (dur < 0.001) dur = 0.001;
    double fps = (double)T / dur;
    long long win = (long long)rint(fps * 1.0);   // WIN_SEC = 1.0
    if (win < 1) win = 1;
    long long hop = (long long)rint(fps * 0.5);   // HOP_SEC = 0.5
    if (hop < 1) hop = 1;
    long long n = ((long long)T >= win) ? (((long long)T - win) / hop + 1) : 0;
    const bool fallback = (n == 0);
    const long long n_eff = fallback ? 1 : n;

    if (tid == 0) {
        M[(size_t)b * maxS + s] = (s < n_eff) ? 1.0f : 0.0f;
    }

    float4* out = S4 + ((size_t)b * maxS + s) * D4;

    if (s >= n_eff) {
        // masked/padded slot: reference zeroes it; d_out is poisoned each call
        if (g == 0) out[lane] = make_float4(0.f, 0.f, 0.f, 0.f);
        return;  // whole block exits before any __syncthreads
    }

    long long start = fallback ? 0 : (long long)s * hop;
    long long end   = fallback ? (long long)T : start + win;
    if (start > T) start = T;
    if (end   > T) end   = T;
    long long cnt = end - start;
    if (cnt < 1) cnt = 1;

    const float4* base = H4 + (size_t)b * T * D4 + lane;

    float ax = 0.f, ay = 0.f, az = 0.f, aw = 0.f;
    float bx = 0.f, by = 0.f, bz = 0.f, bw = 0.f;

    // group g covers rows start+g, start+g+RG, ... ; 8 loads in flight
    long long t = start + g;
    for (; t + 7 * RG < end; t += 8 * RG) {
        float4 v0 = base[(t + 0 * RG) * D4];
        float4 v1 = base[(t + 1 * RG) * D4];
        float4 v2 = base[(t + 2 * RG) * D4];
        float4 v3 = base[(t + 3 * RG) * D4];
        float4 v4 = base[(t + 4 * RG) * D4];
        float4 v5 = base[(t + 5 * RG) * D4];
        float4 v6 = base[(t + 6 * RG) * D4];
        float4 v7 = base[(t + 7 * RG) * D4];
        ax += v0.x + v1.x + v2.x + v3.x;
        ay += v0.y + v1.y + v2.y + v3.y;
        az += v0.z + v1.z + v2.z + v3.z;
        aw += v0.w + v1.w + v2.w + v3.w;
        bx += v4.x + v5.x + v6.x + v7.x;
        by += v4.y + v5.y + v6.y + v7.y;
        bz += v4.z + v5.z + v6.z + v7.z;
        bw += v4.w + v5.w + v6.w + v7.w;
    }
    for (; t < end; t += RG) {
        float4 v = base[t * D4];
        ax += v.x; ay += v.y; az += v.z; aw += v.w;
    }

    __shared__ float4 part[RG][D4];
    part[g][lane] = make_float4(ax + bx, ay + by, az + bz, aw + bw);
    __syncthreads();

    if (g == 0) {
        float4 p0 = part[0][lane];
        float4 p1 = part[1][lane];
        float4 p2 = part[2][lane];
        float4 p3 = part[3][lane];
        const float c = (float)cnt;
        out[lane] = make_float4((p0.x + p1.x + p2.x + p3.x) / c,
                                (p0.y + p1.y + p2.y + p3.y) / c,
                                (p0.z + p1.z + p2.z + p3.z) / c,
                                (p0.w + p1.w + p2.w + p3.w) / c);
    }
}

extern "C" void kernel_launch(void* const* d_in, const int* in_sizes, int n_in,
                              void* d_out, int out_size, void* d_ws, size_t ws_size,
                              hipStream_t stream) {
    const float* H    = (const float*)d_in[0];
    const float* lens = (const float*)d_in[1];

    const int B = in_sizes[1];                 // 32
    const int D = 768;
    const int T = in_sizes[0] / (B * D);       // 1500
    const int maxS = out_size / (B * (D + 1)); // out = B*maxS*D + B*maxS

    float* S = (float*)d_out;
    float* M = S + (size_t)B * maxS * D;

    dim3 grid(B * maxS);
    seg_mean_kernel<<<grid, BDIM, 0, stream>>>(
        (const float4*)H, lens, (float4*)S, M, T, maxS);
}